// Round 2
// baseline (517.278 us; speedup 1.0000x reference)
//
#include <hip/hip_runtime.h>
#include <math.h>

#define B_N 8
#define A_N 120000
#define C_N 80
#define G_N 32

// workspace layout:
//   acc[0..7]   = per-sample cls loss sum
//   acc[8..15]  = per-sample reg loss sum
//   acc[16..23] = per-sample num_pos (float)
//   byte offset 128: state[B_N*A_N] (signed char): -2 neg, -1 ignore, 0..79 pos class

__device__ __forceinline__ float smoothl1(float d) {
    return (d <= (1.0f / 9.0f)) ? 4.5f * d * d : d - (0.5f / 9.0f);
}

__device__ __forceinline__ float focal_term(float p, bool ispos) {
    float q  = 1.0f - p;
    float t  = ispos ? q : p;       // focal base: (1-p) for pos, p for neg
    float lg = ispos ? p : q;       // log argument
    float al = ispos ? 0.25f : 0.75f;
    // alpha * t^1.5 * (-log(clip(lg, 1e-6)))
    return al * t * sqrtf(t) * (-__logf(fmaxf(lg, 1e-6f)));
}

__global__ void init_kernel(float* __restrict__ acc) {
    if (threadIdx.x < 24) acc[threadIdx.x] = 0.0f;
}

__global__ void assign_kernel(const float* __restrict__ anchors,
                              const float* __restrict__ regressions,
                              const float* __restrict__ boxes,
                              const int*   __restrict__ labels,
                              signed char* __restrict__ state,
                              float*       __restrict__ acc) {
    __shared__ float4 sbox[G_N];
    __shared__ int    slab[G_N];
    __shared__ float  sarea[G_N];
    __shared__ float2 sred[4];

    const int b   = blockIdx.y;
    const int tid = threadIdx.x;

    if (tid < G_N) {
        float4 bx = ((const float4*)boxes)[b * G_N + tid];
        sbox[tid]  = bx;
        slab[tid]  = labels[b * G_N + tid];
        sarea[tid] = (bx.z - bx.x) * (bx.w - bx.y);
    }
    __syncthreads();

    const int a = blockIdx.x * blockDim.x + tid;
    float my_reg = 0.0f;
    float my_pos = 0.0f;

    if (a < A_N) {
        float4 an = ((const float4*)anchors)[a];
        float area_a = (an.z - an.x) * (an.w - an.y);
        float best = -1.0f;
        int bestg = 0;
        #pragma unroll 8
        for (int g = 0; g < G_N; ++g) {
            float4 bx = sbox[g];
            float ltx = fmaxf(an.x, bx.x);
            float lty = fmaxf(an.y, bx.y);
            float rbx = fminf(an.z, bx.z);
            float rby = fminf(an.w, bx.w);
            float w = fmaxf(rbx - ltx, 0.0f);
            float h = fmaxf(rby - lty, 0.0f);
            float inter = w * h;
            float iou = inter / (area_a + sarea[g] - inter);
            if (iou > best) { best = iou; bestg = g; }   // strict > : first-max like jnp.argmax
        }

        signed char st;
        if (best >= 0.5f) {
            st = (signed char)slab[bestg];
            my_pos = 1.0f;
            float4 bx = sbox[bestg];
            float aw  = an.z - an.x;
            float ah  = an.w - an.y;
            float acx = an.x + 0.5f * aw;
            float acy = an.y + 0.5f * ah;
            float gwr = bx.z - bx.x;
            float ghr = bx.w - bx.y;
            float gcx = bx.x + 0.5f * gwr;
            float gcy = bx.y + 0.5f * ghr;
            float gw  = fmaxf(gwr, 1.0f);
            float gh  = fmaxf(ghr, 1.0f);
            float t0 = (gcx - acx) / aw;
            float t1 = (gcy - acy) / ah;
            float t2 = __logf(gw / aw);
            float t3 = __logf(gh / ah);
            float4 rg = ((const float4*)regressions)[(size_t)b * A_N + a];
            my_reg = smoothl1(fabsf(t0 - rg.x)) + smoothl1(fabsf(t1 - rg.y))
                   + smoothl1(fabsf(t2 - rg.z)) + smoothl1(fabsf(t3 - rg.w));
        } else {
            st = (best < 0.4f) ? (signed char)(-2) : (signed char)(-1);
        }
        state[(size_t)b * A_N + a] = st;
    }

    // block reduce (my_reg, my_pos): 4 waves of 64
    #pragma unroll
    for (int off = 32; off > 0; off >>= 1) {
        my_reg += __shfl_down(my_reg, off);
        my_pos += __shfl_down(my_pos, off);
    }
    if ((tid & 63) == 0) sred[tid >> 6] = make_float2(my_reg, my_pos);
    __syncthreads();
    if (tid == 0) {
        float r = sred[0].x + sred[1].x + sred[2].x + sred[3].x;
        float p = sred[0].y + sred[1].y + sred[2].y + sred[3].y;
        atomicAdd(&acc[8 + b],  r);
        atomicAdd(&acc[16 + b], p);
    }
}

__global__ void cls_kernel(const float*       __restrict__ cls,
                           const signed char* __restrict__ state,
                           float*             __restrict__ acc) {
    __shared__ float sred[4];
    const int b = blockIdx.y;
    const float4*      p  = (const float4*)(cls + (size_t)b * A_N * C_N);
    const signed char* st = state + (size_t)b * A_N;

    const int n4 = A_N * C_N / 4;  // 2,400,000
    float sum = 0.0f;
    for (int i = blockIdx.x * blockDim.x + threadIdx.x; i < n4;
         i += gridDim.x * blockDim.x) {
        int a     = i / 20;
        int cbase = (i - a * 20) * 4;
        int s = st[a];
        if (s == -1) continue;                // ignore anchor: zero contribution
        float4 v = p[i];
        sum += focal_term(v.x, s == cbase);
        sum += focal_term(v.y, s == cbase + 1);
        sum += focal_term(v.z, s == cbase + 2);
        sum += focal_term(v.w, s == cbase + 3);
    }

    #pragma unroll
    for (int off = 32; off > 0; off >>= 1) sum += __shfl_down(sum, off);
    if ((threadIdx.x & 63) == 0) sred[threadIdx.x >> 6] = sum;
    __syncthreads();
    if (threadIdx.x == 0) {
        atomicAdd(&acc[b], sred[0] + sred[1] + sred[2] + sred[3]);
    }
}

__global__ void finalize_kernel(const float* __restrict__ acc,
                                float*       __restrict__ out) {
    if (threadIdx.x == 0 && blockIdx.x == 0) {
        float cl = 0.0f, rl = 0.0f;
        #pragma unroll
        for (int b = 0; b < B_N; ++b) {
            float np = fmaxf(acc[16 + b], 1.0f);
            cl += acc[b] / np;
            rl += acc[8 + b] / (4.0f * np);
        }
        out[0] = cl * (1.0f / B_N);
        out[1] = rl * (1.0f / B_N);
    }
}

extern "C" void kernel_launch(void* const* d_in, const int* in_sizes, int n_in,
                              void* d_out, int out_size, void* d_ws, size_t ws_size,
                              hipStream_t stream) {
    const float* cls = (const float*)d_in[0];   // [8,120000,80]
    const float* reg = (const float*)d_in[1];   // [8,120000,4]
    const float* anc = (const float*)d_in[2];   // [1,120000,4]
    const float* box = (const float*)d_in[3];   // [8,32,4]
    const int*   lab = (const int*)d_in[4];     // [8,32]
    float* out = (float*)d_out;                 // [2]

    float*       acc   = (float*)d_ws;
    signed char* state = (signed char*)d_ws + 128;

    hipLaunchKernelGGL(init_kernel, dim3(1), dim3(32), 0, stream, acc);

    dim3 g1((A_N + 255) / 256, B_N);
    hipLaunchKernelGGL(assign_kernel, g1, dim3(256), 0, stream,
                       anc, reg, box, lab, state, acc);

    dim3 g2(1200, B_N);
    hipLaunchKernelGGL(cls_kernel, g2, dim3(256), 0, stream, cls, state, acc);

    hipLaunchKernelGGL(finalize_kernel, dim3(1), dim3(64), 0, stream, acc, out);
}

// Round 3
// 461.272 us; speedup vs baseline: 1.1214x; 1.1214x over previous
//
#include <hip/hip_runtime.h>
#include <math.h>

#define B_N 8
#define A_N 120000
#define C_N 80
#define G_N 32

// workspace layout (d_ws):
//   acc[0..7]   = per-sample cls loss sum
//   acc[8..15]  = per-sample reg loss sum
//   acc[16..23] = per-sample num_pos (float)

__device__ __forceinline__ float smoothl1(float d) {
    return (d <= (1.0f / 9.0f)) ? 4.5f * d * d : d - (0.5f / 9.0f);
}

__device__ __forceinline__ float focal_term(float p, bool ispos) {
    float q  = 1.0f - p;
    float t  = ispos ? q : p;       // focal base: (1-p) for pos, p for neg
    float lg = ispos ? p : q;       // log argument
    float al = ispos ? 0.25f : 0.75f;
    // alpha * t^1.5 * (-log(clip(lg, 1e-6)))
    return al * t * sqrtf(t) * (-__logf(fmaxf(lg, 1e-6f)));
}

__global__ void init_kernel(float* __restrict__ acc) {
    if (threadIdx.x < 24) acc[threadIdx.x] = 0.0f;
}

// One block = 256 anchors of one sample. Phase A: assignment + reg loss into
// LDS state. Phase B: stream the block's contiguous 256x80-float cls region
// (coalesced float4), assignment read from LDS. No global state round-trip.
__global__ __launch_bounds__(256) void fused_kernel(
        const float* __restrict__ anchors,
        const float* __restrict__ regressions,
        const float* __restrict__ cls,
        const float* __restrict__ boxes,
        const int*   __restrict__ labels,
        float*       __restrict__ acc) {
    __shared__ float4      sbox[G_N];
    __shared__ int         slab[G_N];
    __shared__ float       sarea[G_N];
    __shared__ signed char sstate[256];   // -2 neg, -1 ignore/OOB, 0..79 pos class
    __shared__ float2      sred2[4];
    __shared__ float       sred[4];

    const int b      = blockIdx.y;
    const int tid    = threadIdx.x;
    const int base_a = blockIdx.x << 8;

    if (tid < G_N) {
        float4 bx = ((const float4*)boxes)[b * G_N + tid];
        sbox[tid]  = bx;
        slab[tid]  = labels[b * G_N + tid];
        sarea[tid] = (bx.z - bx.x) * (bx.w - bx.y);
    }
    __syncthreads();

    // ---- Phase A: per-anchor assignment + regression loss ----
    const int a = base_a + tid;
    float my_reg = 0.0f;
    float my_pos = 0.0f;
    signed char st = -1;                  // OOB anchors contribute nothing

    if (a < A_N) {
        float4 an = ((const float4*)anchors)[a];
        float area_a = (an.z - an.x) * (an.w - an.y);
        float best = -1.0f;
        int bestg = 0;
        #pragma unroll 8
        for (int g = 0; g < G_N; ++g) {
            float4 bx = sbox[g];
            float ltx = fmaxf(an.x, bx.x);
            float lty = fmaxf(an.y, bx.y);
            float rbx = fminf(an.z, bx.z);
            float rby = fminf(an.w, bx.w);
            float w = fmaxf(rbx - ltx, 0.0f);
            float h = fmaxf(rby - lty, 0.0f);
            float inter = w * h;
            float iou = inter / (area_a + sarea[g] - inter);
            if (iou > best) { best = iou; bestg = g; }  // strict > : first-max like jnp.argmax
        }

        if (best >= 0.5f) {
            st = (signed char)slab[bestg];
            my_pos = 1.0f;
            float4 bx = sbox[bestg];
            float aw  = an.z - an.x;
            float ah  = an.w - an.y;
            float acx = an.x + 0.5f * aw;
            float acy = an.y + 0.5f * ah;
            float gwr = bx.z - bx.x;
            float ghr = bx.w - bx.y;
            float gcx = bx.x + 0.5f * gwr;
            float gcy = bx.y + 0.5f * ghr;
            float gw  = fmaxf(gwr, 1.0f);
            float gh  = fmaxf(ghr, 1.0f);
            float t0 = (gcx - acx) / aw;
            float t1 = (gcy - acy) / ah;
            float t2 = __logf(gw / aw);
            float t3 = __logf(gh / ah);
            float4 rg = ((const float4*)regressions)[(size_t)b * A_N + a];
            my_reg = smoothl1(fabsf(t0 - rg.x)) + smoothl1(fabsf(t1 - rg.y))
                   + smoothl1(fabsf(t2 - rg.z)) + smoothl1(fabsf(t3 - rg.w));
        } else {
            st = (best < 0.4f) ? (signed char)(-2) : (signed char)(-1);
        }
    }
    sstate[tid] = st;

    #pragma unroll
    for (int off = 32; off > 0; off >>= 1) {
        my_reg += __shfl_down(my_reg, off);
        my_pos += __shfl_down(my_pos, off);
    }
    if ((tid & 63) == 0) sred2[tid >> 6] = make_float2(my_reg, my_pos);
    __syncthreads();   // publishes sstate + sred2
    if (tid == 0) {
        float r = sred2[0].x + sred2[1].x + sred2[2].x + sred2[3].x;
        float p = sred2[0].y + sred2[1].y + sred2[2].y + sred2[3].y;
        atomicAdd(&acc[8 + b],  r);
        atomicAdd(&acc[16 + b], p);
    }

    // ---- Phase B: focal loss over this block's cls region ----
    const int n_anch = min(256, A_N - base_a);
    const int n4 = n_anch * 20;           // float4 groups in this block's region
    const float4* p4 = (const float4*)(cls + (size_t)b * A_N * C_N) + (size_t)base_a * 20;

    float sum = 0.0f;
    for (int i = tid; i < n4; i += 256) {
        int al    = i / 20;
        int cbase = (i - al * 20) * 4;
        int s = sstate[al];
        if (s == -1) continue;            // ignore anchor
        float4 v = p4[i];
        sum += focal_term(v.x, s == cbase);
        sum += focal_term(v.y, s == cbase + 1);
        sum += focal_term(v.z, s == cbase + 2);
        sum += focal_term(v.w, s == cbase + 3);
    }

    #pragma unroll
    for (int off = 32; off > 0; off >>= 1) sum += __shfl_down(sum, off);
    if ((tid & 63) == 0) sred[tid >> 6] = sum;
    __syncthreads();
    if (tid == 0) {
        atomicAdd(&acc[b], sred[0] + sred[1] + sred[2] + sred[3]);
    }
}

__global__ void finalize_kernel(const float* __restrict__ acc,
                                float*       __restrict__ out) {
    if (threadIdx.x == 0 && blockIdx.x == 0) {
        float cl = 0.0f, rl = 0.0f;
        #pragma unroll
        for (int b = 0; b < B_N; ++b) {
            float np = fmaxf(acc[16 + b], 1.0f);
            cl += acc[b] / np;
            rl += acc[8 + b] / (4.0f * np);
        }
        out[0] = cl * (1.0f / B_N);
        out[1] = rl * (1.0f / B_N);
    }
}

extern "C" void kernel_launch(void* const* d_in, const int* in_sizes, int n_in,
                              void* d_out, int out_size, void* d_ws, size_t ws_size,
                              hipStream_t stream) {
    const float* cls = (const float*)d_in[0];   // [8,120000,80]
    const float* reg = (const float*)d_in[1];   // [8,120000,4]
    const float* anc = (const float*)d_in[2];   // [1,120000,4]
    const float* box = (const float*)d_in[3];   // [8,32,4]
    const int*   lab = (const int*)d_in[4];     // [8,32]
    float* out = (float*)d_out;                 // [2]

    float* acc = (float*)d_ws;

    hipLaunchKernelGGL(init_kernel, dim3(1), dim3(32), 0, stream, acc);

    dim3 g((A_N + 255) / 256, B_N);             // 469 x 8 blocks
    hipLaunchKernelGGL(fused_kernel, g, dim3(256), 0, stream,
                       anc, reg, cls, box, lab, acc);

    hipLaunchKernelGGL(finalize_kernel, dim3(1), dim3(64), 0, stream, acc, out);
}

// Round 5
// 456.934 us; speedup vs baseline: 1.1321x; 1.0095x over previous
//
#include <hip/hip_runtime.h>
#include <math.h>

#define B_N 8
#define A_N 120000
#define C_N 80
#define G_N 32
#define NBX 469                 // ceil(A_N/256)
#define NB  (NBX * B_N)         // 3752 blocks

typedef float f4_t __attribute__((ext_vector_type(4)));   // native vec for nontemporal builtin

// workspace layout (d_ws), floats:
//   [0      .. NB)    per-block cls partial
//   [NB     .. 2*NB)  per-block reg partial
//   [2*NB   .. 3*NB)  per-block num_pos partial
// fused_kernel writes every slot it owns; finalize reads only those. No init needed.

__device__ __forceinline__ float smoothl1(float d) {
    return (d <= (1.0f / 9.0f)) ? 4.5f * d * d : d - (0.5f / 9.0f);
}

__device__ __forceinline__ float focal_term(float p, bool ispos) {
    float q  = 1.0f - p;
    float t  = ispos ? q : p;       // focal base: (1-p) for pos, p for neg
    float lg = ispos ? p : q;       // log argument
    float al = ispos ? 0.25f : 0.75f;
    // alpha * t^1.5 * (-log(clip(lg, 1e-6)))
    return al * t * sqrtf(t) * (-__logf(fmaxf(lg, 1e-6f)));
}

// One block = 256 anchors of one sample. Phase A: assignment + reg loss into
// LDS state. Phase B: stream the block's contiguous 256x80-float cls region
// (coalesced nontemporal float4, branch-free), assignment read from LDS.
// Per-block partials to ws — no atomics, deterministic.
__global__ __launch_bounds__(256) void fused_kernel(
        const float* __restrict__ anchors,
        const float* __restrict__ regressions,
        const float* __restrict__ cls,
        const float* __restrict__ boxes,
        const int*   __restrict__ labels,
        float*       __restrict__ ws) {
    __shared__ float4      sbox[G_N];
    __shared__ int         slab[G_N];
    __shared__ float       sarea[G_N];
    __shared__ signed char sstate[256];   // -2 neg, -1 ignore/OOB, 0..79 pos class
    __shared__ float2      sred2[4];
    __shared__ float       sred[4];

    const int b      = blockIdx.y;
    const int tid    = threadIdx.x;
    const int base_a = blockIdx.x << 8;
    const int blk    = b * NBX + blockIdx.x;

    if (tid < G_N) {
        float4 bx = ((const float4*)boxes)[b * G_N + tid];
        sbox[tid]  = bx;
        slab[tid]  = labels[b * G_N + tid];
        sarea[tid] = (bx.z - bx.x) * (bx.w - bx.y);
    }
    __syncthreads();

    // ---- Phase A: per-anchor assignment + regression loss ----
    const int a = base_a + tid;
    float my_reg = 0.0f;
    float my_pos = 0.0f;
    signed char st = -1;                  // OOB anchors contribute nothing

    if (a < A_N) {
        float4 an = ((const float4*)anchors)[a];
        float area_a = (an.z - an.x) * (an.w - an.y);
        float best = -1.0f;
        int bestg = 0;
        #pragma unroll 8
        for (int g = 0; g < G_N; ++g) {
            float4 bx = sbox[g];
            float ltx = fmaxf(an.x, bx.x);
            float lty = fmaxf(an.y, bx.y);
            float rbx = fminf(an.z, bx.z);
            float rby = fminf(an.w, bx.w);
            float w = fmaxf(rbx - ltx, 0.0f);
            float h = fmaxf(rby - lty, 0.0f);
            float inter = w * h;
            float iou = inter / (area_a + sarea[g] - inter);
            if (iou > best) { best = iou; bestg = g; }  // strict > : first-max like jnp.argmax
        }

        if (best >= 0.5f) {
            st = (signed char)slab[bestg];
            my_pos = 1.0f;
            float4 bx = sbox[bestg];
            float aw  = an.z - an.x;
            float ah  = an.w - an.y;
            float acx = an.x + 0.5f * aw;
            float acy = an.y + 0.5f * ah;
            float gwr = bx.z - bx.x;
            float ghr = bx.w - bx.y;
            float gcx = bx.x + 0.5f * gwr;
            float gcy = bx.y + 0.5f * ghr;
            float gw  = fmaxf(gwr, 1.0f);
            float gh  = fmaxf(ghr, 1.0f);
            float t0 = (gcx - acx) / aw;
            float t1 = (gcy - acy) / ah;
            float t2 = __logf(gw / aw);
            float t3 = __logf(gh / ah);
            float4 rg = ((const float4*)regressions)[(size_t)b * A_N + a];
            my_reg = smoothl1(fabsf(t0 - rg.x)) + smoothl1(fabsf(t1 - rg.y))
                   + smoothl1(fabsf(t2 - rg.z)) + smoothl1(fabsf(t3 - rg.w));
        } else {
            st = (best < 0.4f) ? (signed char)(-2) : (signed char)(-1);
        }
    }
    sstate[tid] = st;

    #pragma unroll
    for (int off = 32; off > 0; off >>= 1) {
        my_reg += __shfl_down(my_reg, off);
        my_pos += __shfl_down(my_pos, off);
    }
    if ((tid & 63) == 0) sred2[tid >> 6] = make_float2(my_reg, my_pos);
    __syncthreads();   // publishes sstate + sred2
    if (tid == 0) {
        ws[NB + blk]     = sred2[0].x + sred2[1].x + sred2[2].x + sred2[3].x;
        ws[2 * NB + blk] = sred2[0].y + sred2[1].y + sred2[2].y + sred2[3].y;
    }

    // ---- Phase B: focal loss over this block's cls region (branch-free) ----
    const int n_anch = min(256, A_N - base_a);
    const int n4 = n_anch * 20;           // float4 groups in this block's region
    const f4_t* p4 = (const f4_t*)(cls + (size_t)b * A_N * C_N) + (size_t)base_a * 20;

    float sum = 0.0f;
    #pragma unroll 4
    for (int i = tid; i < n4; i += 256) {
        int al    = i / 20;
        int cbase = (i - al * 20) * 4;
        int s = sstate[al];
        f4_t v = __builtin_nontemporal_load(&p4[i]);
        float m = (s == -1) ? 0.0f : 1.0f;   // ignore anchors contribute 0
        sum += m * (focal_term(v.x, s == cbase)
                  + focal_term(v.y, s == cbase + 1)
                  + focal_term(v.z, s == cbase + 2)
                  + focal_term(v.w, s == cbase + 3));
    }

    #pragma unroll
    for (int off = 32; off > 0; off >>= 1) sum += __shfl_down(sum, off);
    if ((tid & 63) == 0) sred[tid >> 6] = sum;
    __syncthreads();
    if (tid == 0) {
        ws[blk] = sred[0] + sred[1] + sred[2] + sred[3];
    }
}

__global__ __launch_bounds__(256) void finalize_kernel(
        const float* __restrict__ ws, float* __restrict__ out) {
    __shared__ float s0[4], s1[4], s2[4];
    const int tid = threadIdx.x;
    float cl = 0.0f, rl = 0.0f;

    for (int b = 0; b < B_N; ++b) {
        float sc = 0.0f, sr = 0.0f, sp = 0.0f;
        for (int i = tid; i < NBX; i += 256) {
            sc += ws[b * NBX + i];
            sr += ws[NB + b * NBX + i];
            sp += ws[2 * NB + b * NBX + i];
        }
        #pragma unroll
        for (int off = 32; off > 0; off >>= 1) {
            sc += __shfl_down(sc, off);
            sr += __shfl_down(sr, off);
            sp += __shfl_down(sp, off);
        }
        if ((tid & 63) == 0) { s0[tid >> 6] = sc; s1[tid >> 6] = sr; s2[tid >> 6] = sp; }
        __syncthreads();
        if (tid == 0) {
            float c = s0[0] + s0[1] + s0[2] + s0[3];
            float r = s1[0] + s1[1] + s1[2] + s1[3];
            float p = s2[0] + s2[1] + s2[2] + s2[3];
            float np = fmaxf(p, 1.0f);
            cl += c / np;
            rl += r / (4.0f * np);
        }
        __syncthreads();
    }
    if (tid == 0) {
        out[0] = cl * (1.0f / B_N);
        out[1] = rl * (1.0f / B_N);
    }
}

extern "C" void kernel_launch(void* const* d_in, const int* in_sizes, int n_in,
                              void* d_out, int out_size, void* d_ws, size_t ws_size,
                              hipStream_t stream) {
    const float* cls = (const float*)d_in[0];   // [8,120000,80]
    const float* reg = (const float*)d_in[1];   // [8,120000,4]
    const float* anc = (const float*)d_in[2];   // [1,120000,4]
    const float* box = (const float*)d_in[3];   // [8,32,4]
    const int*   lab = (const int*)d_in[4];     // [8,32]
    float* out = (float*)d_out;                 // [2]

    float* ws = (float*)d_ws;

    dim3 g(NBX, B_N);                            // 469 x 8 blocks
    hipLaunchKernelGGL(fused_kernel, g, dim3(256), 0, stream,
                       anc, reg, cls, box, lab, ws);

    hipLaunchKernelGGL(finalize_kernel, dim3(1), dim3(256), 0, stream, ws, out);
}